// Round 6
// baseline (284.912 us; speedup 1.0000x reference)
//
#include <hip/hip_runtime.h>
#include <hip/hip_cooperative_groups.h>
#include <stdint.h>

namespace cg = cooperative_groups;

#define OH 250
#define OW 250
#define NPTS (OH*OW)        // 62500
#define NSEG 4              // y batches only (x-side is mathematically dead; verified R2-R5)
#define D 147               // 3*7*7
#define CH 3
#define IMH 256
#define IMW 256
#define NITER 17            // ceil(log2(62500)) + 1, per reference
#define NBUCK 4096
#define SIG0 12.124355652982141  // sqrt(147): projection stddev model (bucketing only)
#define GRD 256
#define BLK 512

typedef unsigned long long u64;
typedef unsigned int u32;

// workspace layout (bytes, all 8-aligned)
#define OFF_REC   0UL        // u64[4*62500] = 2,000,000
#define OFF_SREC  2000000UL  // u64[4*62500] = 2,000,000
#define OFF_A     4000000UL  // u32[4*62500] = 1,000,000
#define OFF_HIST  5000000UL  // u32[4*4096]  = 65,536
#define OFF_BASES 5065536UL  // u32[4*4097]  = 65,552
#define OFF_CURS  5131088UL  // u32[4*4096]  = 65,536
#define OFF_WTS   5196624UL  // double[4*147]= 4,704 (fallback path only)
#define OFF_SUMS  5201328UL  // u64[4]       = 32
#define WS_NEED   5201360UL

__device__ __forceinline__ u64 packd(double f) {
  u64 u = (u64)__double_as_longlong(f);
  return (u & 0x8000000000000000ULL) ? ~u : (u | 0x8000000000000000ULL);
}

// bucket from the 47-bit-truncated transformed key (identical everywhere; monotone with key)
__device__ __forceinline__ int bucket_of(u64 rec) {
  u64 t = rec & ~0x1FFFFULL;
  u64 bits = (t & 0x8000000000000000ULL) ? (t & 0x7FFFFFFFFFFFFFFFULL) : ~t;
  double v = __longlong_as_double((long long)bits);
  double z = (v + 4.0 * SIG0) * ((double)NBUCK / (8.0 * SIG0));
  int b = (z <= 0.0) ? 0 : (int)z;
  if (b > NBUCK - 1) b = NBUCK - 1;
  return b;
}

// ===================== fused cooperative kernel =====================
__global__ __launch_bounds__(BLK, 2) void fused_kern(
    const float* __restrict__ y, const float* __restrict__ rnd,
    u64* __restrict__ recs, u64* __restrict__ srec, u32* __restrict__ aidx,
    u32* __restrict__ hist, u32* __restrict__ bases, u32* __restrict__ curs,
    u64* __restrict__ sums, float* __restrict__ out) {
  cg::grid_group grid = cg::this_grid();
  __shared__ double w[NSEG][D];
  __shared__ __align__(16) char sh[32768];
  float (*tile)[22][38] = (float (*)[22][38])sh;   // 10032 B   (conv)
  u32* lhist = (u32*)(sh + 10048);                 // 16384 B   (conv)
  u64 (*bbuf)[512] = (u64 (*)[512])sh;             // 32768 B   (bsort, overlaid)
  u32* spart = (u32*)sh;                           // 2048 B    (scan, overlaid)
  __shared__ long long lsums[NSEG];

  int tid = threadIdx.x, bid = blockIdx.x;
  int lane = tid & 63, wid = tid >> 6;

  // ---- Phase W: per-block weights (rand/std ddof=1, f64; scale-exact) + zero hist/sums ----
  if (wid < NSEG) {
    int s = wid;
    double v0 = (double)rnd[s * D + lane];                       // lane < 64 < 147 always
    double v1 = (lane + 64 < D) ? (double)rnd[s * D + lane + 64] : 0.0;
    double v2 = (lane + 128 < D) ? (double)rnd[s * D + lane + 128] : 0.0;
    double sm = v0 + v1 + v2;
    for (int o = 32; o > 0; o >>= 1) sm += __shfl_down(sm, o, 64);
    sm = __shfl(sm, 0, 64);
    double mean = sm / (double)D;
    double d0 = v0 - mean;
    double d1 = (lane + 64 < D) ? v1 - mean : 0.0;
    double d2 = (lane + 128 < D) ? v2 - mean : 0.0;
    double ss = d0 * d0 + d1 * d1 + d2 * d2;
    for (int o = 32; o > 0; o >>= 1) ss += __shfl_down(ss, o, 64);
    ss = __shfl(ss, 0, 64);
    double stdv = sqrt(ss / (double)(D - 1));
    w[s][lane] = v0 / stdv;
    if (lane + 64 < D) w[s][lane + 64] = v1 / stdv;
    if (lane + 128 < D) w[s][lane + 128] = v2 / stdv;
  }
  {
    int g = bid * BLK + tid;
    if (g < NSEG * NBUCK) hist[g] = 0u;
    if (g < NSEG) sums[g] = 0ULL;
  }
  grid.sync();

  // ---- Phase B: conv (3x7x7, f64) + LDS bucket histogram. 512 tiles, 2/block, same seg ----
  for (int k = tid; k < NBUCK; k += BLK) lhist[k] = 0u;
  int T0 = 2 * bid;
  int seg = T0 >> 7;                               // both tiles of a block share seg
  const float* in = y + (size_t)seg * CH * IMH * IMW;
  __syncthreads();
  for (int r = 0; r < 2; ++r) {
    int tsub = (T0 + r) & 127;
    int bi = (tsub >> 3) * 16, bj = (tsub & 7) * 32;
    for (int t = tid; t < CH * 22 * 38; t += BLK) {
      int c = t / (22 * 38), rem = t % (22 * 38);
      int rr = rem / 38, cc = rem % 38;
      int rI = bi + rr, cI = bj + cc;
      float v = 0.f;
      if (rI < IMH && cI < IMW) v = in[((size_t)c * IMH + rI) * IMW + cI];
      tile[c][rr][cc] = v;
    }
    __syncthreads();
    int ty = tid >> 5, tx = tid & 31;
    int i = bi + ty, j = bj + tx;
    if (i < OH && j < OW) {
      double acc = 0.0;
      #pragma unroll
      for (int c = 0; c < CH; ++c)
        #pragma unroll
        for (int ph = 0; ph < 7; ++ph)
          #pragma unroll
          for (int pw = 0; pw < 7; ++pw)
            acc = fma((double)tile[c][ty + ph][tx + pw], w[seg][c * 49 + ph * 7 + pw], acc);
      int n = i * OW + j;
      u64 rec = (packd(acc) & ~0x1FFFFULL) | (u64)(u32)n;
      recs[(size_t)seg * NPTS + n] = rec;
      atomicAdd(&lhist[bucket_of(rec)], 1u);
    }
    __syncthreads();
  }
  for (int k = tid; k < NBUCK; k += BLK) {
    u32 c = lhist[k];
    if (c) atomicAdd(&hist[seg * NBUCK + k], c);
  }
  grid.sync();

  // ---- Phase C: per-seg exclusive scan of 4096 bucket counts (blocks 0..3) ----
  if (bid < NSEG) {
    int s = bid;
    u32 c[8]; u32 run = 0;
    #pragma unroll
    for (int m = 0; m < 8; ++m) { c[m] = hist[s * NBUCK + 8 * tid + m]; run += c[m]; }
    spart[tid] = run;
    __syncthreads();
    for (int off = 1; off < BLK; off <<= 1) {
      u32 v = (tid >= off) ? spart[tid - off] : 0u;
      __syncthreads();
      spart[tid] += v;
      __syncthreads();
    }
    u32 ex = spart[tid] - run;
    #pragma unroll
    for (int m = 0; m < 8; ++m) {
      bases[s * (NBUCK + 1) + 8 * tid + m] = ex;
      curs[s * NBUCK + 8 * tid + m] = ex;
      ex += c[m];
    }
    if (tid == BLK - 1) bases[s * (NBUCK + 1) + NBUCK] = ex;   // == NPTS
  }
  grid.sync();

  // ---- Phase D: unstable scatter into bucket ranges ----
  {
    int g = bid * BLK + tid;
    #pragma unroll
    for (int rep = 0; rep < 2; ++rep) {
      int e = g + rep * (GRD * BLK);
      if (e < NSEG * NPTS) {
        u64 rec = recs[e];
        int s = e / NPTS;
        int bk = bucket_of(rec);
        u32 pos = atomicAdd(&curs[s * NBUCK + bk], 1u);
        srec[(size_t)s * NPTS + pos] = rec;
      }
    }
  }
  grid.sync();

  // ---- Phase E: one wave per bucket, exact rank sort (distinct records) ----
  {
    int gw = bid * 8 + wid;                        // 2048 waves, 8 buckets each
    for (int q = 0; q < 8; ++q) {
      int B = gw + q * 2048;
      int s = B >> 12, bk = B & (NBUCK - 1);
      u32 b0 = bases[s * (NBUCK + 1) + bk];
      u32 b1 = bases[s * (NBUCK + 1) + bk + 1];
      int n = (int)(b1 - b0);
      const u64* src = srec + (size_t)s * NPTS + b0;
      u32* dst = aidx + (size_t)s * NPTS + b0;
      __syncthreads();                             // uniform: protect bbuf reuse
      if (n <= 512) for (int i = lane; i < n; i += 64) bbuf[wid][i] = src[i];
      __syncthreads();                             // uniform: publish bbuf
      if (n <= 512) {
        for (int i = lane; i < n; i += 64) {
          u64 x = bbuf[wid][i]; int rk = 0;
          for (int jj = 0; jj < n; ++jj) rk += (bbuf[wid][jj] < x);  // LDS broadcast
          dst[rk] = (u32)(x & 0x1FFFFULL);
        }
      } else {                                     // exact fallback, never expected
        for (int i = lane; i < n; i += 64) {
          u64 x = src[i]; int rk = 0;
          for (int jj = 0; jj < n; ++jj) rk += (src[jj] < x);
          dst[rk] = (u32)(x & 0x1FFFFULL);
        }
      }
    }
  }
  grid.sync();

  // ---- Phase F: exact replica bisect_left-on-unsorted + nearest; dual search per thread ----
  if (tid < NSEG) lsums[tid] = 0;
  __syncthreads();
  {
    int g = bid * BLK + tid;
    int v1g = g + GRD * BLK;
    bool a1 = v1g < NSEG * NPTS;
    int s0 = g / NPTS, s1 = a1 ? v1g / NPTS : 0;
    int vv0 = g - s0 * NPTS, vv1 = v1g - s1 * NPTS;
    const u32* A0 = aidx + (size_t)s0 * NPTS;
    const u32* A1 = aidx + (size_t)s1 * NPTS;
    int lo0 = 0, hi0 = NPTS, lo1 = 0, hi1 = NPTS;
    #pragma unroll
    for (int it = 0; it < NITER; ++it) {
      int mid0 = (lo0 + hi0) >> 1, mid1 = (lo1 + hi1) >> 1;
      int cm0 = mid0 > NPTS - 1 ? NPTS - 1 : mid0;
      int cm1 = mid1 > NPTS - 1 ? NPTS - 1 : mid1;
      int am0 = (int)A0[cm0];
      int am1 = (int)A1[cm1];
      if (lo0 < hi0) { if (am0 < vv0) lo0 = mid0 + 1; else hi0 = mid0; }
      if (lo1 < hi1) { if (am1 < vv1) lo1 = mid1 + 1; else hi1 = mid1; }
    }
    long long t0, t1;
    {
      int pi = lo0 - 1; if (pi < 0) pi = 0; if (pi > NPTS - 1) pi = NPTS - 1;
      int ci = lo0;     if (ci > NPTS - 1) ci = NPTS - 1;
      int ap = (int)A0[pi], aa = (int)A0[ci];
      int d1 = vv0 - ap; if (d1 < 0) d1 = -d1;
      int d2 = vv0 - aa; if (d2 < 0) d2 = -d2;
      bool tp = (lo0 > 0) && ((lo0 == NPTS) || (d1 < d2));
      long long dd = (long long)(vv0 - (tp ? ap : aa));
      t0 = dd * dd;
    }
    {
      int pi = lo1 - 1; if (pi < 0) pi = 0; if (pi > NPTS - 1) pi = NPTS - 1;
      int ci = lo1;     if (ci > NPTS - 1) ci = NPTS - 1;
      int ap = (int)A1[pi], aa = (int)A1[ci];
      int d1 = vv1 - ap; if (d1 < 0) d1 = -d1;
      int d2 = vv1 - aa; if (d2 < 0) d2 = -d2;
      bool tp = (lo1 > 0) && ((lo1 == NPTS) || (d1 < d2));
      long long dd = (long long)(vv1 - (tp ? ap : aa));
      t1 = dd * dd;
    }
    atomicAdd((u64*)&lsums[s0], (u64)t0);
    if (a1) atomicAdd((u64*)&lsums[s1], (u64)t1);
  }
  __syncthreads();
  if (tid < NSEG && lsums[tid]) atomicAdd(&sums[tid], (u64)lsums[tid]);
  grid.sync();

  if (bid == 0 && tid == 0) {
    double l = 0.0;
    for (int b = 0; b < NSEG; ++b) l += (double)(long long)sums[b] / (double)NPTS;
    out[0] = (float)(l / 4.0);
  }
}

// ===================== fallback path (R5, proven) =====================
__global__ __launch_bounds__(256) void prep_kern(const float* __restrict__ rnd,
                                                 double* __restrict__ wts,
                                                 u32* __restrict__ hist,
                                                 u64* __restrict__ sums) {
  int t = threadIdx.x;
  if (blockIdx.x < 4) {
    __shared__ double red[256];
    int b = blockIdx.x;
    double val = (t < D) ? (double)rnd[b * D + t] : 0.0;
    red[t] = val;
    __syncthreads();
    for (int s = 128; s > 0; s >>= 1) { if (t < s) red[t] += red[t + s]; __syncthreads(); }
    double mean = red[0] / (double)D;
    __syncthreads();
    double dv = (t < D) ? (val - mean) : 0.0;
    red[t] = dv * dv;
    __syncthreads();
    for (int s = 128; s > 0; s >>= 1) { if (t < s) red[t] += red[t + s]; __syncthreads(); }
    double stdv = sqrt(red[0] / (double)(D - 1));
    if (t < D) wts[b * D + t] = val / stdv;
  } else {
    int g = (blockIdx.x - 4) * 256 + t;
    if (g < NSEG * NBUCK) hist[g] = 0u;
    if (g < 4) sums[g] = 0ULL;
  }
}

__global__ __launch_bounds__(256) void conv_kern(const float* __restrict__ y,
                                                 const double* __restrict__ wts,
                                                 u64* __restrict__ recs,
                                                 u32* __restrict__ hist) {
  __shared__ float tile[CH][22][22];
  __shared__ double w[D];
  __shared__ u32 lh[NBUCK];
  int b = blockIdx.z;
  const float* in = y + (size_t)b * CH * IMH * IMW;
  int bi = blockIdx.y * 16, bj = blockIdx.x * 16;
  int tid = threadIdx.y * 16 + threadIdx.x;
  for (int k = tid; k < NBUCK; k += 256) lh[k] = 0u;
  if (tid < D) w[tid] = wts[b * D + tid];
  for (int c = 0; c < CH; ++c)
    for (int t = tid; t < 22 * 22; t += 256) {
      int rr = t / 22, cc = t - rr * 22;
      int r = bi + rr, col = bj + cc;
      float v = 0.f;
      if (r < IMH && col < IMW) v = in[((size_t)c * IMH + r) * IMW + col];
      tile[c][rr][cc] = v;
    }
  __syncthreads();
  int i = bi + threadIdx.y, j = bj + threadIdx.x;
  if (i < OH && j < OW) {
    double acc = 0.0;
    #pragma unroll
    for (int c = 0; c < CH; ++c)
      #pragma unroll
      for (int ph = 0; ph < 7; ++ph)
        #pragma unroll
        for (int pw = 0; pw < 7; ++pw)
          acc = fma((double)tile[c][threadIdx.y + ph][threadIdx.x + pw],
                    w[c * 49 + ph * 7 + pw], acc);
    int n = i * OW + j;
    u64 rec = (packd(acc) & ~0x1FFFFULL) | (u64)(u32)n;
    recs[(size_t)b * NPTS + n] = rec;
    atomicAdd(&lh[bucket_of(rec)], 1u);
  }
  __syncthreads();
  for (int k = tid; k < NBUCK; k += 256) {
    u32 c = lh[k];
    if (c) atomicAdd(&hist[b * NBUCK + k], c);
  }
}

__global__ __launch_bounds__(1024) void scan_kern(const u32* __restrict__ hist,
                                                  u32* __restrict__ bases,
                                                  u32* __restrict__ curs) {
  __shared__ u32 part[1024];
  int seg = blockIdx.x, t = threadIdx.x;
  u32 c[4];
  #pragma unroll
  for (int m = 0; m < 4; ++m) c[m] = hist[seg * NBUCK + 4 * t + m];
  u32 s = c[0] + c[1] + c[2] + c[3];
  part[t] = s;
  __syncthreads();
  for (int off = 1; off < 1024; off <<= 1) {
    u32 v = (t >= off) ? part[t - off] : 0u;
    __syncthreads();
    part[t] += v;
    __syncthreads();
  }
  u32 ex = part[t] - s;
  #pragma unroll
  for (int m = 0; m < 4; ++m) {
    bases[seg * (NBUCK + 1) + 4 * t + m] = ex;
    curs[seg * NBUCK + 4 * t + m] = ex;
    ex += c[m];
  }
  if (t == 1023) bases[seg * (NBUCK + 1) + NBUCK] = ex;
}

__global__ __launch_bounds__(256) void scatter_kern(const u64* __restrict__ recs,
                                                    u32* __restrict__ curs,
                                                    u64* __restrict__ srec) {
  int seg = blockIdx.y;
  int e = blockIdx.x * 256 + threadIdx.x;
  if (e < NPTS) {
    u64 rec = recs[(size_t)seg * NPTS + e];
    int bk = bucket_of(rec);
    u32 pos = atomicAdd(&curs[seg * NBUCK + bk], 1u);
    srec[(size_t)seg * NPTS + pos] = rec;
  }
}

__global__ __launch_bounds__(512) void bsort_kern(const u64* __restrict__ srec,
                                                  const u32* __restrict__ bases,
                                                  u32* __restrict__ a) {
  __shared__ u64 buf[8][512];
  int wid = threadIdx.x >> 6, lane = threadIdx.x & 63;
  int w = blockIdx.x * 8 + wid;
  int seg = w >> 12, bk = w & (NBUCK - 1);
  u32 b0 = bases[seg * (NBUCK + 1) + bk];
  u32 b1 = bases[seg * (NBUCK + 1) + bk + 1];
  int n = (int)(b1 - b0);
  const u64* src = srec + (size_t)seg * NPTS + b0;
  u32* dst = a + (size_t)seg * NPTS + b0;
  bool uselds = (n <= 512);
  if (uselds) for (int i = lane; i < n; i += 64) buf[wid][i] = src[i];
  __syncthreads();
  if (uselds) {
    for (int i = lane; i < n; i += 64) {
      u64 x = buf[wid][i];
      int r = 0;
      for (int j = 0; j < n; ++j) r += (buf[wid][j] < x);
      dst[r] = (u32)(x & 0x1FFFFULL);
    }
  } else {
    for (int i = lane; i < n; i += 64) {
      u64 x = src[i];
      int r = 0;
      for (int j = 0; j < n; ++j) r += (src[j] < x);
      dst[r] = (u32)(x & 0x1FFFFULL);
    }
  }
}

__global__ __launch_bounds__(256) void loss_kern(const u32* __restrict__ a_all,
                                                 u64* __restrict__ sums) {
  int b = blockIdx.y;
  int v = blockIdx.x * 256 + threadIdx.x;
  const u32* a = a_all + (size_t)b * NPTS;
  long long term = 0;
  if (v < NPTS) {
    int lo = 0, hi = NPTS;
    #pragma unroll
    for (int it = 0; it < NITER; ++it) {
      int mid = (lo + hi) >> 1;
      int cm = mid > NPTS - 1 ? NPTS - 1 : mid;
      int am = (int)a[cm];
      bool go = lo < hi;
      if (go) {
        if (am < v) lo = mid + 1;
        else        hi = mid;
      }
    }
    int pi = lo - 1; if (pi < 0) pi = 0; if (pi > NPTS - 1) pi = NPTS - 1;
    int ci = lo;     if (ci > NPTS - 1) ci = NPTS - 1;
    int ap = (int)a[pi], aa = (int)a[ci];
    int d1 = v - ap; if (d1 < 0) d1 = -d1;
    int d2 = v - aa; if (d2 < 0) d2 = -d2;
    bool take_prev = (lo > 0) && ((lo == NPTS) || (d1 < d2));
    int nearest = take_prev ? ap : aa;
    long long d = (long long)(v - nearest);
    term = d * d;
  }
  for (int off = 32; off > 0; off >>= 1) term += __shfl_down(term, off, 64);
  __shared__ long long part[4];
  int lane = threadIdx.x & 63, wid = threadIdx.x >> 6;
  if (lane == 0) part[wid] = term;
  __syncthreads();
  if (threadIdx.x == 0) {
    long long tot = part[0] + part[1] + part[2] + part[3];
    atomicAdd(&sums[b], (u64)tot);
  }
}

__global__ void final_kern(const u64* __restrict__ sums, float* __restrict__ out) {
  if (threadIdx.x == 0 && blockIdx.x == 0) {
    double l = 0.0;
    for (int b = 0; b < 4; ++b) l += (double)(long long)sums[b] / (double)NPTS;
    out[0] = (float)(l / 4.0);
  }
}

__global__ void guard_kern(float* __restrict__ out) {
  if (threadIdx.x == 0 && blockIdx.x == 0) out[0] = 9.0e12f;
}

extern "C" void kernel_launch(void* const* d_in, const int* in_sizes, int n_in,
                              void* d_out, int out_size, void* d_ws, size_t ws_size,
                              hipStream_t stream) {
  (void)in_sizes; (void)n_in; (void)out_size;
  if (ws_size < WS_NEED) { guard_kern<<<1, 64, 0, stream>>>((float*)d_out); return; }
  const float* y   = (const float*)d_in[1];
  const float* rnd = (const float*)d_in[2];

  char* ws = (char*)d_ws;
  u64* recs   = (u64*)(ws + OFF_REC);
  u64* srec   = (u64*)(ws + OFF_SREC);
  u32* aidx   = (u32*)(ws + OFF_A);
  u32* hist   = (u32*)(ws + OFF_HIST);
  u32* bases  = (u32*)(ws + OFF_BASES);
  u32* curs   = (u32*)(ws + OFF_CURS);
  double* wts = (double*)(ws + OFF_WTS);
  u64* sums   = (u64*)(ws + OFF_SUMS);
  float* out  = (float*)d_out;

  void* args[] = { (void*)&y, (void*)&rnd, (void*)&recs, (void*)&srec, (void*)&aidx,
                   (void*)&hist, (void*)&bases, (void*)&curs, (void*)&sums, (void*)&out };
  hipError_t err = hipLaunchCooperativeKernel((const void*)fused_kern,
                                              dim3(GRD), dim3(BLK), args, 0, stream);
  if (err == hipSuccess) return;

  // fallback: proven R5 multi-kernel path
  prep_kern<<<68, 256, 0, stream>>>(rnd, wts, hist, sums);
  conv_kern<<<dim3(16, 16, NSEG), dim3(16, 16), 0, stream>>>(y, wts, recs, hist);
  scan_kern<<<NSEG, 1024, 0, stream>>>(hist, bases, curs);
  scatter_kern<<<dim3((NPTS + 255) / 256, NSEG), 256, 0, stream>>>(recs, curs, srec);
  bsort_kern<<<NSEG * NBUCK / 8, 512, 0, stream>>>(srec, bases, aidx);
  loss_kern<<<dim3((NPTS + 255) / 256, NSEG), 256, 0, stream>>>(aidx, sums);
  final_kern<<<1, 64, 0, stream>>>(sums, out);
}

// Round 7
// 226.062 us; speedup vs baseline: 1.2603x; 1.2603x over previous
//
#include <hip/hip_runtime.h>
#include <stdint.h>

#define OH 250
#define OW 250
#define NPTS (OH*OW)        // 62500
#define NSEG 4              // y batches only (x-side is mathematically dead; verified R2-R6)
#define D 147               // 3*7*7
#define CH 3
#define IMH 256
#define IMW 256
#define NITER 17            // ceil(log2(62500)) + 1, per reference
#define NBUCK 4096
#define SIG0 12.124355652982141  // sqrt(147): projection stddev model (bucketing only)

typedef unsigned long long u64;
typedef unsigned int u32;

// workspace layout (bytes)
#define OFF_REC   0UL        // u64[4*62500] = 2,000,000
#define OFF_SREC  2000000UL  // u64[4*62500] = 2,000,000
#define OFF_A     4000000UL  // u32[4*62500] = 1,000,000
#define OFF_CTRL  5000000UL  // control region, zeroed by hipMemsetAsync each call:
#define OFF_HIST  5000000UL  //   u32[4*4096] = 65,536
#define OFF_BASES 5065536UL  //   u32[4*4097] = 65,552
#define OFF_CURS  5131088UL  //   u32[4*4096] = 65,536
#define OFF_SUMS  5196624UL  //   u64[4]      = 32
#define OFF_TICK  5196656UL  //   u32[2]      = 8
#define CTRL_LEN  196664UL
#define WS_NEED   5196664UL

__device__ __forceinline__ u64 packd(double f) {
  u64 u = (u64)__double_as_longlong(f);
  return (u & 0x8000000000000000ULL) ? ~u : (u | 0x8000000000000000ULL);
}

// bucket from the 47-bit-truncated transformed key (identical everywhere; monotone with key)
__device__ __forceinline__ int bucket_of(u64 rec) {
  u64 t = rec & ~0x1FFFFULL;
  u64 bits = (t & 0x8000000000000000ULL) ? (t & 0x7FFFFFFFFFFFFFFFULL) : ~t;
  double v = __longlong_as_double((long long)bits);
  double z = (v + 4.0 * SIG0) * ((double)NBUCK / (8.0 * SIG0));
  int b = (z <= 0.0) ? 0 : (int)z;
  if (b > NBUCK - 1) b = NBUCK - 1;
  return b;
}

// ---- conv (3x7x7, f64) + per-block weights + fused hist + last-block scan tail ----
// grid dim3(16,16,NSEG), block 256. hist/curs/sums/tick pre-zeroed by memset.
__global__ __launch_bounds__(256) void conv_kern(const float* __restrict__ y,
                                                 const float* __restrict__ rnd,
                                                 u64* __restrict__ recs,
                                                 u32* __restrict__ hist,
                                                 u32* __restrict__ bases,
                                                 u32* __restrict__ tick) {
  __shared__ float tile[CH][22][22];
  __shared__ double w[D];
  __shared__ u32 lh[NBUCK];
  __shared__ u32 spart[256];
  __shared__ u32 rank_s;
  int b = blockIdx.z;
  const float* in = y + (size_t)b * CH * IMH * IMW;
  int bi = blockIdx.y * 16, bj = blockIdx.x * 16;
  int tid = threadIdx.y * 16 + threadIdx.x;
  int lane = tid & 63;

  // per-block weights: rand/std(ddof=1) in f64. Butterfly order differs from a tree
  // reduction only in last-ulp of std -> uniform positive scale per batch -> ranks exact.
  {
    double v0 = (double)rnd[b * D + lane];            // lane   0..63  < 147
    double v1 = (double)rnd[b * D + lane + 64];       // lane+64 64..127 < 147
    double v2 = (lane + 128 < D) ? (double)rnd[b * D + lane + 128] : 0.0;
    double sm = v0 + v1 + v2;
    #pragma unroll
    for (int o = 32; o > 0; o >>= 1) sm += __shfl_xor(sm, o, 64);
    double mean = sm / (double)D;
    double d0 = v0 - mean, d1 = v1 - mean;
    double d2 = (lane + 128 < D) ? (v2 - mean) : 0.0;
    double ss = d0 * d0 + d1 * d1 + d2 * d2;
    #pragma unroll
    for (int o = 32; o > 0; o >>= 1) ss += __shfl_xor(ss, o, 64);
    double stdv = sqrt(ss / (double)(D - 1));
    // all 4 waves write identical values - benign
    w[lane] = v0 / stdv;
    w[lane + 64] = v1 / stdv;
    if (lane + 128 < D) w[lane + 128] = v2 / stdv;
  }
  for (int k = tid; k < NBUCK; k += 256) lh[k] = 0u;
  for (int c = 0; c < CH; ++c)
    for (int t = tid; t < 22 * 22; t += 256) {
      int rr = t / 22, cc = t - rr * 22;
      int r = bi + rr, col = bj + cc;
      float v = 0.f;
      if (r < IMH && col < IMW) v = in[((size_t)c * IMH + r) * IMW + col];
      tile[c][rr][cc] = v;
    }
  __syncthreads();
  int i = bi + threadIdx.y, j = bj + threadIdx.x;
  if (i < OH && j < OW) {
    double acc = 0.0;
    #pragma unroll
    for (int c = 0; c < CH; ++c)
      #pragma unroll
      for (int ph = 0; ph < 7; ++ph)
        #pragma unroll
        for (int pw = 0; pw < 7; ++pw)
          acc = fma((double)tile[c][threadIdx.y + ph][threadIdx.x + pw],
                    w[c * 49 + ph * 7 + pw], acc);
    int n = i * OW + j;
    u64 rec = (packd(acc) & ~0x1FFFFULL) | (u64)(u32)n;
    recs[(size_t)b * NPTS + n] = rec;
    atomicAdd(&lh[bucket_of(rec)], 1u);
  }
  __syncthreads();
  for (int k = tid; k < NBUCK; k += 256) {
    u32 c = lh[k];
    if (c) atomicAdd(&hist[b * NBUCK + k], c);
  }
  // ---- last-block ticket: winner computes the 4-seg bucket scan -> bases ----
  __threadfence();                                  // release our hist updates
  if (tid == 0) rank_s = atomicAdd(&tick[0], 1u);
  __syncthreads();
  if (rank_s != 16 * 16 * NSEG - 1) return;
  __threadfence();                                  // acquire all hist updates
  for (int s2 = 0; s2 < NSEG; ++s2) {
    u32 c[16]; u32 run = 0;
    #pragma unroll
    for (int m = 0; m < 16; ++m) {
      c[m] = __hip_atomic_load(&hist[s2 * NBUCK + 16 * tid + m],
                               __ATOMIC_RELAXED, __HIP_MEMORY_SCOPE_AGENT);
      run += c[m];
    }
    spart[tid] = run;
    __syncthreads();
    for (int off = 1; off < 256; off <<= 1) {
      u32 v = (tid >= off) ? spart[tid - off] : 0u;
      __syncthreads();
      spart[tid] += v;
      __syncthreads();
    }
    u32 ex = spart[tid] - run;
    #pragma unroll
    for (int m = 0; m < 16; ++m) {
      bases[s2 * (NBUCK + 1) + 16 * tid + m] = ex;
      ex += c[m];
    }
    if (tid == 255) bases[s2 * (NBUCK + 1) + NBUCK] = ex;   // == NPTS
    __syncthreads();
  }
}

// ---- unstable scatter into bucket ranges (curs pre-zeroed; pos = base + cursor) ----
__global__ __launch_bounds__(256) void scatter_kern(const u64* __restrict__ recs,
                                                    const u32* __restrict__ bases,
                                                    u32* __restrict__ curs,
                                                    u64* __restrict__ srec) {
  int seg = blockIdx.y;
  int e = blockIdx.x * 256 + threadIdx.x;
  if (e < NPTS) {
    u64 rec = recs[(size_t)seg * NPTS + e];
    int bk = bucket_of(rec);
    u32 pos = bases[seg * (NBUCK + 1) + bk] + atomicAdd(&curs[seg * NBUCK + bk], 1u);
    srec[(size_t)seg * NPTS + pos] = rec;
  }
}

// ---- one wave per bucket: exact rank sort (records all distinct), write argsort idx ----
__global__ __launch_bounds__(512) void bsort_kern(const u64* __restrict__ srec,
                                                  const u32* __restrict__ bases,
                                                  u32* __restrict__ a) {
  __shared__ u64 buf[8][512];
  int wid = threadIdx.x >> 6, lane = threadIdx.x & 63;
  int w = blockIdx.x * 8 + wid;
  int seg = w >> 12, bk = w & (NBUCK - 1);
  u32 b0 = bases[seg * (NBUCK + 1) + bk];
  u32 b1 = bases[seg * (NBUCK + 1) + bk + 1];
  int n = (int)(b1 - b0);
  const u64* src = srec + (size_t)seg * NPTS + b0;
  u32* dst = a + (size_t)seg * NPTS + b0;
  bool uselds = (n <= 512);
  if (uselds) for (int i = lane; i < n; i += 64) buf[wid][i] = src[i];
  __syncthreads();
  if (uselds) {
    for (int i = lane; i < n; i += 64) {
      u64 x = buf[wid][i];
      int r = 0;
      for (int j = 0; j < n; ++j) r += (buf[wid][j] < x);   // LDS broadcast, conflict-free
      dst[r] = (u32)(x & 0x1FFFFULL);
    }
  } else {                                        // exact fallback, never expected
    for (int i = lane; i < n; i += 64) {
      u64 x = src[i];
      int r = 0;
      for (int j = 0; j < n; ++j) r += (src[j] < x);
      dst[r] = (u32)(x & 0x1FFFFULL);
    }
  }
}

// ---- exact replica bisect_left-on-unsorted + nearest; sum over v=0..N-1; ticket final ----
__global__ __launch_bounds__(256) void loss_kern(const u32* __restrict__ a_all,
                                                 u64* __restrict__ sums,
                                                 u32* __restrict__ tick,
                                                 float* __restrict__ out,
                                                 int nblocks) {
  int b = blockIdx.y;
  int v = blockIdx.x * 256 + threadIdx.x;
  const u32* a = a_all + (size_t)b * NPTS;
  long long term = 0;
  if (v < NPTS) {
    int lo = 0, hi = NPTS;
    #pragma unroll
    for (int it = 0; it < NITER; ++it) {
      int mid = (lo + hi) >> 1;
      int cm = mid > NPTS - 1 ? NPTS - 1 : mid;
      int am = (int)a[cm];
      bool go = lo < hi;
      if (go) {
        if (am < v) lo = mid + 1;
        else        hi = mid;
      }
    }
    int pi = lo - 1; if (pi < 0) pi = 0; if (pi > NPTS - 1) pi = NPTS - 1;
    int ci = lo;     if (ci > NPTS - 1) ci = NPTS - 1;
    int ap = (int)a[pi], aa = (int)a[ci];
    int d1 = v - ap; if (d1 < 0) d1 = -d1;
    int d2 = v - aa; if (d2 < 0) d2 = -d2;
    bool take_prev = (lo > 0) && ((lo == NPTS) || (d1 < d2));
    int nearest = take_prev ? ap : aa;
    long long d = (long long)(v - nearest);
    term = d * d;
  }
  for (int off = 32; off > 0; off >>= 1) term += __shfl_down(term, off, 64);
  __shared__ long long part[4];
  __shared__ u32 rank_s;
  int lane = threadIdx.x & 63, wid = threadIdx.x >> 6;
  if (lane == 0) part[wid] = term;
  __syncthreads();
  if (threadIdx.x == 0) {
    long long tot = part[0] + part[1] + part[2] + part[3];
    atomicAdd(&sums[b], (u64)tot);
    __threadfence();                               // release our sum
    rank_s = atomicAdd(&tick[1], 1u);
  }
  __syncthreads();
  if (rank_s == (u32)(nblocks - 1) && threadIdx.x == 0) {
    __threadfence();                               // acquire all sums
    double l = 0.0;
    for (int s = 0; s < NSEG; ++s) {
      u64 sv = __hip_atomic_load(&sums[s], __ATOMIC_RELAXED, __HIP_MEMORY_SCOPE_AGENT);
      l += (double)(long long)sv / (double)NPTS;
    }
    out[0] = (float)(l / 4.0);
  }
}

__global__ void guard_kern(float* __restrict__ out) {
  if (threadIdx.x == 0 && blockIdx.x == 0) out[0] = 9.0e12f;
}

extern "C" void kernel_launch(void* const* d_in, const int* in_sizes, int n_in,
                              void* d_out, int out_size, void* d_ws, size_t ws_size,
                              hipStream_t stream) {
  (void)in_sizes; (void)n_in; (void)out_size;
  if (ws_size < WS_NEED) { guard_kern<<<1, 64, 0, stream>>>((float*)d_out); return; }
  const float* y   = (const float*)d_in[1];
  const float* rnd = (const float*)d_in[2];

  char* ws = (char*)d_ws;
  u64* recs   = (u64*)(ws + OFF_REC);
  u64* srec   = (u64*)(ws + OFF_SREC);
  u32* aidx   = (u32*)(ws + OFF_A);
  u32* hist   = (u32*)(ws + OFF_HIST);
  u32* bases  = (u32*)(ws + OFF_BASES);
  u32* curs   = (u32*)(ws + OFF_CURS);
  u64* sums   = (u64*)(ws + OFF_SUMS);
  u32* tick   = (u32*)(ws + OFF_TICK);
  float* out  = (float*)d_out;

  hipMemsetAsync(ws + OFF_CTRL, 0, CTRL_LEN, stream);
  conv_kern<<<dim3(16, 16, NSEG), dim3(16, 16), 0, stream>>>(y, rnd, recs, hist, bases, tick);
  scatter_kern<<<dim3((NPTS + 255) / 256, NSEG), 256, 0, stream>>>(recs, bases, curs, srec);
  bsort_kern<<<NSEG * NBUCK / 8, 512, 0, stream>>>(srec, bases, aidx);
  int nb = ((NPTS + 255) / 256) * NSEG;
  loss_kern<<<dim3((NPTS + 255) / 256, NSEG), 256, 0, stream>>>(aidx, sums, tick, out, nb);
}

// Round 8
// 119.251 us; speedup vs baseline: 2.3892x; 1.8957x over previous
//
#include <hip/hip_runtime.h>
#include <stdint.h>

#define OH 250
#define OW 250
#define NPTS (OH*OW)        // 62500
#define NSEG 4              // y batches only (x-side is mathematically dead; verified R2-R7)
#define D 147               // 3*7*7
#define CH 3
#define IMH 256
#define IMW 256
#define NITER 17            // ceil(log2(62500)) + 1, per reference
#define NBUCK 4096
#define CAP 256             // slots per bucket; central-bucket mean ~49, P(>256) ~ 0
#define SIG0 12.124355652982141  // sqrt(147): projection stddev model (bucketing only)

typedef unsigned long long u64;
typedef unsigned int u32;

// workspace layout (bytes)
#define OFF_SREC  0UL         // u64[4*4096*256] = 33,554,432
#define OFF_A     33554432UL  // u32[4*62500]    = 1,000,000
#define OFF_CTRL  34554432UL  // zeroed by hipMemsetAsync each call:
#define OFF_CURS  34554432UL  //   u32[4*4096] = 65,536
#define OFF_SUMS  34619968UL  //   u64[4]      = 32
#define OFF_OFLOW 34620000UL  //   u32[1]      = 4
#define CTRL_LEN  65572UL
#define OFF_BASES 34620008UL  // u32[4*4097] = 65,552 (written by scan)
#define WS_NEED   34685560UL

__device__ __forceinline__ u64 packd(double f) {
  u64 u = (u64)__double_as_longlong(f);
  return (u & 0x8000000000000000ULL) ? ~u : (u | 0x8000000000000000ULL);
}

// bucket from the 47-bit-truncated transformed key (monotone with key order)
__device__ __forceinline__ int bucket_of(u64 rec) {
  u64 t = rec & ~0x1FFFFULL;
  u64 bits = (t & 0x8000000000000000ULL) ? (t & 0x7FFFFFFFFFFFFFFFULL) : ~t;
  double v = __longlong_as_double((long long)bits);
  double z = (v + 4.0 * SIG0) * ((double)NBUCK / (8.0 * SIG0));
  int b = (z <= 0.0) ? 0 : (int)z;
  if (b > NBUCK - 1) b = NBUCK - 1;
  return b;
}

// ---- conv (3x7x7, f64) + per-block weights + DIRECT bucket scatter (no fences) ----
// grid dim3(16,16,NSEG), block 16x16. curs/sums/oflow pre-zeroed by memset.
__global__ __launch_bounds__(256) void conv_kern(const float* __restrict__ y,
                                                 const float* __restrict__ rnd,
                                                 u64* __restrict__ srec,
                                                 u32* __restrict__ curs,
                                                 u32* __restrict__ oflow) {
  __shared__ float tile[CH][22][22];
  __shared__ double w[D];
  int b = blockIdx.z;
  const float* in = y + (size_t)b * CH * IMH * IMW;
  int bi = blockIdx.y * 16, bj = blockIdx.x * 16;
  int tid = threadIdx.y * 16 + threadIdx.x;
  int lane = tid & 63;

  // per-block weights: rand/std(ddof=1) in f64. Butterfly order differs from reference
  // only in last-ulp of std -> uniform positive scale per batch -> ranks exact (R6/R7: absmax 0).
  {
    double v0 = (double)rnd[b * D + lane];
    double v1 = (double)rnd[b * D + lane + 64];
    double v2 = (lane + 128 < D) ? (double)rnd[b * D + lane + 128] : 0.0;
    double sm = v0 + v1 + v2;
    #pragma unroll
    for (int o = 32; o > 0; o >>= 1) sm += __shfl_xor(sm, o, 64);
    double mean = sm / (double)D;
    double d0 = v0 - mean, d1 = v1 - mean;
    double d2 = (lane + 128 < D) ? (v2 - mean) : 0.0;
    double ss = d0 * d0 + d1 * d1 + d2 * d2;
    #pragma unroll
    for (int o = 32; o > 0; o >>= 1) ss += __shfl_xor(ss, o, 64);
    double stdv = sqrt(ss / (double)(D - 1));
    w[lane] = v0 / stdv;                    // all 4 waves write identical values - benign
    w[lane + 64] = v1 / stdv;
    if (lane + 128 < D) w[lane + 128] = v2 / stdv;
  }
  for (int c = 0; c < CH; ++c)
    for (int t = tid; t < 22 * 22; t += 256) {
      int rr = t / 22, cc = t - rr * 22;
      int r = bi + rr, col = bj + cc;
      float v = 0.f;
      if (r < IMH && col < IMW) v = in[((size_t)c * IMH + r) * IMW + col];
      tile[c][rr][cc] = v;
    }
  __syncthreads();
  int i = bi + threadIdx.y, j = bj + threadIdx.x;
  if (i < OH && j < OW) {
    double acc = 0.0;
    #pragma unroll
    for (int c = 0; c < CH; ++c)
      #pragma unroll
      for (int ph = 0; ph < 7; ++ph)
        #pragma unroll
        for (int pw = 0; pw < 7; ++pw)
          acc = fma((double)tile[c][threadIdx.y + ph][threadIdx.x + pw],
                    w[c * 49 + ph * 7 + pw], acc);
    int n = i * OW + j;
    u64 rec = (packd(acc) & ~0x1FFFFULL) | (u64)(u32)n;
    int bk = b * NBUCK + bucket_of(rec);
    u32 pos = atomicAdd(&curs[bk], 1u);
    if (pos < CAP) srec[(size_t)bk * CAP + pos] = rec;
    else atomicOr(oflow, 1u);              // exactness tripwire (never expected)
  }
}

// ---- per-seg exclusive scan of 4096 bucket counts -> bases ----
__global__ __launch_bounds__(1024) void scan_kern(const u32* __restrict__ curs,
                                                  u32* __restrict__ bases) {
  __shared__ u32 part[1024];
  int seg = blockIdx.x, t = threadIdx.x;
  u32 c[4];
  #pragma unroll
  for (int m = 0; m < 4; ++m) {
    u32 v = curs[seg * NBUCK + 4 * t + m];
    c[m] = v > CAP ? CAP : v;              // clamp: OOB-safety only (oflow flags exactness)
  }
  u32 s = c[0] + c[1] + c[2] + c[3];
  part[t] = s;
  __syncthreads();
  for (int off = 1; off < 1024; off <<= 1) {
    u32 v = (t >= off) ? part[t - off] : 0u;
    __syncthreads();
    part[t] += v;
    __syncthreads();
  }
  u32 ex = part[t] - s;
  #pragma unroll
  for (int m = 0; m < 4; ++m) {
    bases[seg * (NBUCK + 1) + 4 * t + m] = ex;
    ex += c[m];
  }
  if (t == 1023) bases[seg * (NBUCK + 1) + NBUCK] = ex;
}

// ---- one wave per bucket: exact rank sort (records all distinct), write argsort idx ----
__global__ __launch_bounds__(512) void bsort_kern(const u64* __restrict__ srec,
                                                  const u32* __restrict__ bases,
                                                  u32* __restrict__ a) {
  __shared__ u64 buf[8][CAP];
  int wid = threadIdx.x >> 6, lane = threadIdx.x & 63;
  int B = blockIdx.x * 8 + wid;            // 16384 buckets total
  int seg = B >> 12, bk = B & (NBUCK - 1);
  u32 b0 = bases[seg * (NBUCK + 1) + bk];
  u32 b1 = bases[seg * (NBUCK + 1) + bk + 1];
  int n = (int)(b1 - b0);
  const u64* src = srec + (size_t)B * CAP;
  u32* dst = a + (size_t)seg * NPTS + b0;
  for (int i = lane; i < n; i += 64) buf[wid][i] = src[i];
  __syncthreads();
  for (int i = lane; i < n; i += 64) {
    u64 x = buf[wid][i];
    int r = 0;
    for (int j = 0; j < n; ++j) r += (buf[wid][j] < x);   // LDS broadcast, conflict-free
    dst[r] = (u32)(x & 0x1FFFFULL);
  }
}

// ---- exact replica bisect_left-on-unsorted + nearest; two interleaved searches/thread ----
#define HALF (NSEG * NPTS / 2)             // 125000
__global__ __launch_bounds__(256) void loss_kern(const u32* __restrict__ a_all,
                                                 u64* __restrict__ sums) {
  __shared__ u64 lsums[NSEG];
  int tid = threadIdx.x;
  if (tid < NSEG) lsums[tid] = 0ULL;
  __syncthreads();
  int g = blockIdx.x * 256 + tid;
  if (g < HALF) {
    int g1 = g + HALF;
    int s0 = g / NPTS, s1 = g1 / NPTS;
    int vv0 = g - s0 * NPTS, vv1 = g1 - s1 * NPTS;
    const u32* A0 = a_all + (size_t)s0 * NPTS;
    const u32* A1 = a_all + (size_t)s1 * NPTS;
    int lo0 = 0, hi0 = NPTS, lo1 = 0, hi1 = NPTS;
    #pragma unroll
    for (int it = 0; it < NITER; ++it) {
      int mid0 = (lo0 + hi0) >> 1, mid1 = (lo1 + hi1) >> 1;
      int cm0 = mid0 > NPTS - 1 ? NPTS - 1 : mid0;
      int cm1 = mid1 > NPTS - 1 ? NPTS - 1 : mid1;
      int am0 = (int)A0[cm0];                // two independent dependent-load chains
      int am1 = (int)A1[cm1];
      if (lo0 < hi0) { if (am0 < vv0) lo0 = mid0 + 1; else hi0 = mid0; }
      if (lo1 < hi1) { if (am1 < vv1) lo1 = mid1 + 1; else hi1 = mid1; }
    }
    {
      int pi = lo0 - 1; if (pi < 0) pi = 0; if (pi > NPTS - 1) pi = NPTS - 1;
      int ci = lo0;     if (ci > NPTS - 1) ci = NPTS - 1;
      int ap = (int)A0[pi], aa = (int)A0[ci];
      int d1 = vv0 - ap; if (d1 < 0) d1 = -d1;
      int d2 = vv0 - aa; if (d2 < 0) d2 = -d2;
      bool tp = (lo0 > 0) && ((lo0 == NPTS) || (d1 < d2));
      long long dd = (long long)(vv0 - (tp ? ap : aa));
      atomicAdd(&lsums[s0], (u64)(dd * dd));
    }
    {
      int pi = lo1 - 1; if (pi < 0) pi = 0; if (pi > NPTS - 1) pi = NPTS - 1;
      int ci = lo1;     if (ci > NPTS - 1) ci = NPTS - 1;
      int ap = (int)A1[pi], aa = (int)A1[ci];
      int d1 = vv1 - ap; if (d1 < 0) d1 = -d1;
      int d2 = vv1 - aa; if (d2 < 0) d2 = -d2;
      bool tp = (lo1 > 0) && ((lo1 == NPTS) || (d1 < d2));
      long long dd = (long long)(vv1 - (tp ? ap : aa));
      atomicAdd(&lsums[s1], (u64)(dd * dd));
    }
  }
  __syncthreads();
  if (tid < NSEG && lsums[tid]) atomicAdd(&sums[tid], lsums[tid]);
}

__global__ void final_kern(const u64* __restrict__ sums, const u32* __restrict__ oflow,
                           float* __restrict__ out) {
  if (threadIdx.x == 0 && blockIdx.x == 0) {
    if (oflow[0]) { out[0] = 8.0e12f; return; }   // loud failure, never expected
    double l = 0.0;
    for (int b = 0; b < NSEG; ++b) l += (double)(long long)sums[b] / (double)NPTS;
    out[0] = (float)(l / 4.0);
  }
}

__global__ void guard_kern(float* __restrict__ out) {
  if (threadIdx.x == 0 && blockIdx.x == 0) out[0] = 9.0e12f;
}

extern "C" void kernel_launch(void* const* d_in, const int* in_sizes, int n_in,
                              void* d_out, int out_size, void* d_ws, size_t ws_size,
                              hipStream_t stream) {
  (void)in_sizes; (void)n_in; (void)out_size;
  if (ws_size < WS_NEED) { guard_kern<<<1, 64, 0, stream>>>((float*)d_out); return; }
  const float* y   = (const float*)d_in[1];
  const float* rnd = (const float*)d_in[2];

  char* ws = (char*)d_ws;
  u64* srec   = (u64*)(ws + OFF_SREC);
  u32* aidx   = (u32*)(ws + OFF_A);
  u32* curs   = (u32*)(ws + OFF_CURS);
  u64* sums   = (u64*)(ws + OFF_SUMS);
  u32* oflow  = (u32*)(ws + OFF_OFLOW);
  u32* bases  = (u32*)(ws + OFF_BASES);
  float* out  = (float*)d_out;

  hipMemsetAsync(ws + OFF_CTRL, 0, CTRL_LEN, stream);
  conv_kern<<<dim3(16, 16, NSEG), dim3(16, 16), 0, stream>>>(y, rnd, srec, curs, oflow);
  scan_kern<<<NSEG, 1024, 0, stream>>>(curs, bases);
  bsort_kern<<<NSEG * NBUCK / 8, 512, 0, stream>>>(srec, bases, aidx);
  loss_kern<<<(HALF + 255) / 256, 256, 0, stream>>>(aidx, sums);
  final_kern<<<1, 64, 0, stream>>>(sums, oflow, out);
}